// Round 1
// baseline (4714.548 us; speedup 1.0000x reference)
//
#include <hip/hip_runtime.h>

// QuantumMicroTransformer forward, MI355X (gfx950).
// Pipeline: embed+PE -> [QKV proj -> attn (softmax->exp->renorm->x*sigmoid(x)) -> O proj
//           -> residual + sr_norm(quake fast_inv_sqrt)] x2 -> final GEMM [1024,2048]@[2048,100000].
// GEMMs: bf16 MFMA (16x16x32), fp32 weights converted to bf16 during LDS staging.
// Workspace layout (<=48MB): x_f32(8M) q(8M) k(8M) v(8M) o(8M) x_bf16(4M) attn_bf16(4M).

#define DEVINL __device__ __forceinline__

typedef float f32x4 __attribute__((ext_vector_type(4)));
typedef __bf16 bf16x8 __attribute__((ext_vector_type(8)));

DEVINL unsigned short f2bf(float f) {
  unsigned int u = __float_as_uint(f);
  u += 0x7fffu + ((u >> 16) & 1u);   // round-to-nearest-even
  return (unsigned short)(u >> 16);
}

// ---------------- embed + positional encoding (pe indexed by BATCH, per reference) -------------
__global__ __launch_bounds__(256) void embed_kernel(
    const int* __restrict__ src, const float* __restrict__ emb,
    float* __restrict__ x, unsigned short* __restrict__ xbf) {
  const int row = blockIdx.x;                 // b*512 + s
  const int b = row >> 9;
  const int tok = src[row];
  const float sqrtH = 45.25483399593904f;     // sqrt(2048)
  const float c = -9.210340371976184f / 2048.f;  // -ln(10000)/H
  for (int h = threadIdx.x; h < 2048; h += 256) {
    int i = h >> 1;
    float dv = expf((float)(2 * i) * c);
    float ang = (float)b * dv;
    float pe = (h & 1) ? cosf(ang) : sinf(ang);
    float val = emb[(size_t)tok * 2048 + h] * sqrtH + pe;
    x[(size_t)row * 2048 + h] = val;
    xbf[(size_t)row * 2048 + h] = f2bf(val);
  }
}

// ---------------- bf16 MFMA GEMM: C[M,N] = A_bf16[M,K] @ B_f32[K,N] + bias ---------------------
// K = 2048 fixed. Block tile BM x 128, BK=32, 256 threads (4 waves, 2x2).
// B is converted fp32->bf16 and transposed into LDS [N][K] so frags are contiguous ds_read_b128.
template <int BM>
__global__ __launch_bounds__(256) void gemm_kernel(
    const unsigned short* __restrict__ A, const float* __restrict__ B,
    const float* __restrict__ bias, float* __restrict__ C, const int N) {
  constexpr int K = 2048;
  constexpr int WM = BM / 32;                 // 16x16 frags per wave in M
  __shared__ __align__(16) unsigned short A_lds[BM * 40];   // rows padded to 80B
  __shared__ __align__(16) unsigned short B_lds[128 * 40];

  const int tid = threadIdx.x;
  const int n0 = blockIdx.x * 128;
  const int m0 = blockIdx.y * BM;
  const int w = tid >> 6, lane = tid & 63;
  const int wm = w >> 1, wn = w & 1;
  const int lrow = lane & 15, lk = (lane >> 4) * 8;

  f32x4 acc[WM][4] = {};

  const int n_local = tid & 127;
  const int kq = tid >> 7;                    // 0..1
  const int col = n0 + n_local;
  const bool colok = col < N;

  for (int k0 = 0; k0 < K; k0 += 32) {
    // stage A (bf16, linear copy)
#pragma unroll
    for (int i = 0; i < BM / 64; ++i) {
      int flat = i * 256 + tid;
      int m = flat >> 2, k8 = flat & 3;
      *(uint4*)&A_lds[m * 40 + k8 * 8] =
          *(const uint4*)(A + (size_t)(m0 + m) * K + k0 + k8 * 8);
    }
    // stage B: fp32 -> bf16, transposed into [n][k]
#pragma unroll
    for (int g = 0; g < 4; ++g) {
      int kl = (g * 2 + kq) * 4;
      float f0 = 0.f, f1 = 0.f, f2 = 0.f, f3 = 0.f;
      if (colok) {
        const float* bp = B + (size_t)(k0 + kl) * N + col;
        f0 = bp[0]; f1 = bp[(size_t)N]; f2 = bp[2 * (size_t)N]; f3 = bp[3 * (size_t)N];
      }
      unsigned int lo = (unsigned int)f2bf(f0) | ((unsigned int)f2bf(f1) << 16);
      unsigned int hi = (unsigned int)f2bf(f2) | ((unsigned int)f2bf(f3) << 16);
      *(uint2*)&B_lds[n_local * 40 + kl] = make_uint2(lo, hi);
    }
    __syncthreads();

    bf16x8 af[WM], bfg[4];
#pragma unroll
    for (int mi = 0; mi < WM; ++mi)
      af[mi] = *(const bf16x8*)&A_lds[(wm * (BM / 2) + mi * 16 + lrow) * 40 + lk];
#pragma unroll
    for (int ni = 0; ni < 4; ++ni)
      bfg[ni] = *(const bf16x8*)&B_lds[(wn * 64 + ni * 16 + lrow) * 40 + lk];
#pragma unroll
    for (int mi = 0; mi < WM; ++mi)
#pragma unroll
      for (int ni = 0; ni < 4; ++ni)
        acc[mi][ni] = __builtin_amdgcn_mfma_f32_16x16x32_bf16(af[mi], bfg[ni], acc[mi][ni], 0, 0, 0);
    __syncthreads();
  }

  const int r0 = (lane >> 4) * 4;             // C/D: col = lane&15, row = (lane>>4)*4 + reg
#pragma unroll
  for (int mi = 0; mi < WM; ++mi) {
#pragma unroll
    for (int ni = 0; ni < 4; ++ni) {
      int ccol = n0 + wn * 64 + ni * 16 + lrow;
      if (ccol < N) {
        float bv = bias[ccol];
#pragma unroll
        for (int r = 0; r < 4; ++r) {
          int crow = m0 + wm * (BM / 2) + mi * 16 + r0 + r;
          C[(size_t)crow * N + ccol] = acc[mi][ni][r] + bv;
        }
      }
    }
  }
}

// ---------------- fused attention: scores -> softmax -> exp -> renorm(+eps) -> a2*sigmoid(a2) -> @V
// One thread per query row; K tile (one head, fp32) in LDS; 3-pass score recompute.
__global__ __launch_bounds__(256) void attn_kernel(
    const float* __restrict__ q, const float* __restrict__ k,
    const float* __restrict__ v, unsigned short* __restrict__ o) {
  __shared__ __align__(16) float K_lds[512 * 32];   // 64KB
  const int tid = threadIdx.x;
  const int blk = blockIdx.x;                 // 0..255
  const int bh = blk >> 1, chunk = blk & 1;
  const int b = bh >> 6, h = bh & 63;
  const size_t headoff = (size_t)b * 512 * 2048 + (size_t)h * 32;

  const float* kb = k + headoff;
#pragma unroll
  for (int i = 0; i < 16; ++i) {
    int flat = i * 256 + tid;                 // float4 id (4096 total)
    int j = flat >> 3, d4 = flat & 7;
    *(float4*)&K_lds[j * 32 + d4 * 4] = *(const float4*)(kb + (size_t)j * 2048 + d4 * 4);
  }
  __syncthreads();

  const int row = chunk * 256 + tid;          // s in [0,512)
  const float* qr = q + headoff + (size_t)row * 2048;
  float4 Q[8];
#pragma unroll
  for (int d = 0; d < 8; ++d) Q[d] = *(const float4*)(qr + d * 4);

  const float scale = 0.17677669529663689f;   // 1/sqrt(32)
  auto dot = [&](int j) -> float {
    const float4* kr = (const float4*)&K_lds[j * 32];
    float p0 = 0.f, p1 = 0.f, p2 = 0.f, p3 = 0.f;
#pragma unroll
    for (int d = 0; d < 8; ++d) {
      float4 kk = kr[d];
      p0 = fmaf(Q[d].x, kk.x, p0);
      p1 = fmaf(Q[d].y, kk.y, p1);
      p2 = fmaf(Q[d].z, kk.z, p2);
      p3 = fmaf(Q[d].w, kk.w, p3);
    }
    return ((p0 + p1) + (p2 + p3)) * scale;
  };

  // pass 1: online max + softmax denominator
  float m = -1e30f, denom = 0.f;
  for (int j = 0; j < 512; ++j) {
    float s = dot(j);
    float nm = fmaxf(m, s);
    denom = denom * __expf(m - nm) + __expf(s - nm);
    m = nm;
  }
  const float invd = 1.f / denom;

  // pass 2: sum of exp(softmax)
  float sum_e = 0.f;
  for (int j = 0; j < 512; ++j) {
    float a = __expf(dot(j) - m) * invd;
    sum_e += __expf(a);
  }
  const float inv_se = 1.f / (sum_e + 1e-6f);

  // pass 3: cw = a2*sigmoid(a2), accumulate cw @ V
  float4 accv[8];
#pragma unroll
  for (int d = 0; d < 8; ++d) accv[d] = make_float4(0.f, 0.f, 0.f, 0.f);
  const float* vb = v + headoff;
  for (int j = 0; j < 512; ++j) {
    float a = __expf(dot(j) - m) * invd;
    float e = __expf(a);
    float a2 = e * inv_se;
    float cw = a2 / (1.f + __expf(-a2));
    const float4* vr = (const float4*)(vb + (size_t)j * 2048);
#pragma unroll
    for (int d = 0; d < 8; ++d) {
      float4 vv = vr[d];
      accv[d].x = fmaf(cw, vv.x, accv[d].x);
      accv[d].y = fmaf(cw, vv.y, accv[d].y);
      accv[d].z = fmaf(cw, vv.z, accv[d].z);
      accv[d].w = fmaf(cw, vv.w, accv[d].w);
    }
  }
  unsigned short* orow = o + headoff + (size_t)row * 2048;
#pragma unroll
  for (int d = 0; d < 8; ++d) {
    orow[d * 4 + 0] = f2bf(accv[d].x);
    orow[d * 4 + 1] = f2bf(accv[d].y);
    orow[d * 4 + 2] = f2bf(accv[d].z);
    orow[d * 4 + 3] = f2bf(accv[d].w);
  }
}

// ---------------- residual + sr_norm with quake fast_inv_sqrt (bit-faithful) -------------------
__global__ __launch_bounds__(256) void norm_kernel(
    const float* __restrict__ o, const float* __restrict__ xin,
    const float* __restrict__ w, const float* __restrict__ bb,
    float* __restrict__ xout, unsigned short* __restrict__ xbf) {
  __shared__ float red[4];
  const int row = blockIdx.x, tid = threadIdx.x;
  const float* op = o + (size_t)row * 2048;
  const float* xp = xin + (size_t)row * 2048;
  float4 hv[2];
#pragma unroll
  for (int i = 0; i < 2; ++i) {
    float4 a = *(const float4*)(op + tid * 4 + i * 1024);
    float4 c = *(const float4*)(xp + tid * 4 + i * 1024);
    hv[i] = make_float4(a.x + c.x, a.y + c.y, a.z + c.z, a.w + c.w);
  }
  float s = 0.f;
#pragma unroll
  for (int i = 0; i < 2; ++i) s += hv[i].x + hv[i].y + hv[i].z + hv[i].w;
  for (int off = 32; off; off >>= 1) s += __shfl_down(s, off);
  if ((tid & 63) == 0) red[tid >> 6] = s;
  __syncthreads();
  const float mean = (red[0] + red[1] + red[2] + red[3]) * (1.f / 2048.f);
  __syncthreads();

  float vs = 0.f;
#pragma unroll
  for (int i = 0; i < 2; ++i) {
    float dx = hv[i].x - mean, dy = hv[i].y - mean, dz = hv[i].z - mean, dw = hv[i].w - mean;
    vs += dx * dx + dy * dy + dz * dz + dw * dw;
  }
  for (int off = 32; off; off >>= 1) vs += __shfl_down(vs, off);
  if ((tid & 63) == 0) red[tid >> 6] = vs;
  __syncthreads();
  const float var = (red[0] + red[1] + red[2] + red[3]) * (1.f / 2048.f);

  // quake fast inverse sqrt, exactly as reference
  const float xv = var + 1e-5f;
  int ii = __float_as_int(xv);
  ii = 1597463007 - (ii >> 1);
  float y = __int_as_float(ii);
  y = y * (1.5f - 0.5f * xv * y * y);

#pragma unroll
  for (int i = 0; i < 2; ++i) {
    int c0 = tid * 4 + i * 1024;
    float4 wv = *(const float4*)(w + c0);
    float4 bv = *(const float4*)(bb + c0);
    float r0 = wv.x * ((hv[i].x - mean) * y) + bv.x;
    float r1 = wv.y * ((hv[i].y - mean) * y) + bv.y;
    float r2 = wv.z * ((hv[i].z - mean) * y) + bv.z;
    float r3 = wv.w * ((hv[i].w - mean) * y) + bv.w;
    *(float4*)(xout + (size_t)row * 2048 + c0) = make_float4(r0, r1, r2, r3);
    unsigned short* xb = xbf + (size_t)row * 2048 + c0;
    xb[0] = f2bf(r0); xb[1] = f2bf(r1); xb[2] = f2bf(r2); xb[3] = f2bf(r3);
  }
}

// ---------------- launch -----------------------------------------------------------------------
extern "C" void kernel_launch(void* const* d_in, const int* in_sizes, int n_in,
                              void* d_out, int out_size, void* d_ws, size_t ws_size,
                              hipStream_t stream) {
  const int*   src  = (const int*)d_in[0];
  const float* emb  = (const float*)d_in[1];
  const float* Wq   = (const float*)d_in[2];
  const float* bq   = (const float*)d_in[3];
  const float* Wk   = (const float*)d_in[4];
  const float* bk   = (const float*)d_in[5];
  const float* Wv   = (const float*)d_in[6];
  const float* bv   = (const float*)d_in[7];
  const float* Wo   = (const float*)d_in[8];
  const float* bo   = (const float*)d_in[9];
  const float* nw   = (const float*)d_in[10];
  const float* nb   = (const float*)d_in[11];
  const float* Wout = (const float*)d_in[12];
  const float* bout = (const float*)d_in[13];
  float* out = (float*)d_out;

  char* ws = (char*)d_ws;
  float* x  = (float*)(ws);
  float* qb = (float*)(ws + (8ll << 20));
  float* kb = (float*)(ws + (16ll << 20));
  float* vb = (float*)(ws + (24ll << 20));
  float* ob = (float*)(ws + (32ll << 20));
  unsigned short* xbf = (unsigned short*)(ws + (40ll << 20));
  unsigned short* abf = (unsigned short*)(ws + (44ll << 20));

  embed_kernel<<<1024, 256, 0, stream>>>(src, emb, x, xbf);

  const dim3 gproj(16, 16);   // N=2048/128, M=1024/64
  for (int l = 0; l < 2; ++l) {
    const size_t wo_ = (size_t)l * 2048 * 2048;
    const size_t bo_ = (size_t)l * 2048;
    gemm_kernel<64><<<gproj, 256, 0, stream>>>(xbf, Wq + wo_, bq + bo_, qb, 2048);
    gemm_kernel<64><<<gproj, 256, 0, stream>>>(xbf, Wk + wo_, bk + bo_, kb, 2048);
    gemm_kernel<64><<<gproj, 256, 0, stream>>>(xbf, Wv + wo_, bv + bo_, vb, 2048);
    attn_kernel<<<256, 256, 0, stream>>>(qb, kb, vb, abf);
    gemm_kernel<64><<<gproj, 256, 0, stream>>>(abf, Wo + wo_, bo + bo_, ob, 2048);
    norm_kernel<<<1024, 256, 0, stream>>>(ob, x, nw + bo_, nb + bo_, x, xbf);
  }

  const dim3 gfin((100000 + 127) / 128, 1024 / 128);
  gemm_kernel<128><<<gfin, 256, 0, stream>>>(xbf, Wout, bout, out, 100000);
}

// Round 3
// 2853.401 us; speedup vs baseline: 1.6523x; 1.6523x over previous
//
#include <hip/hip_runtime.h>

// QuantumMicroTransformer forward, MI355X (gfx950).
// GEMMs: bf16 MFMA 16x16x32, register-staged double-buffer (1 barrier/K-tile):
//   load tile t+1 -> regs; compute tile t (hides VMEM latency); cvt+ds_write tile t+1; barrier.
// LDS: 64B rows, 16B chunks XOR-swizzled with (row>>1)&3 on write, inverted on read
//      -> bank-floor ds_read_b128/ds_write_b128 (no excess conflicts).
// Grid M-fastest so blocks sharing a B-slice run concurrently (L2/L3 absorbs B reuse).

#define DEVINL __device__ __forceinline__

typedef float f32x4 __attribute__((ext_vector_type(4)));
typedef __bf16 bf16x8 __attribute__((ext_vector_type(8)));

DEVINL unsigned short f2bf(float f) {
  unsigned int u = __float_as_uint(f);
  u += 0x7fffu + ((u >> 16) & 1u);   // round-to-nearest-even
  return (unsigned short)(u >> 16);
}

// ---------------- embed + positional encoding (pe indexed by BATCH, per reference) -------------
__global__ __launch_bounds__(256) void embed_kernel(
    const int* __restrict__ src, const float* __restrict__ emb,
    float* __restrict__ x, unsigned short* __restrict__ xbf) {
  const int row = blockIdx.x;                 // b*512 + s
  const int b = row >> 9;
  const int tok = src[row];
  const float sqrtH = 45.25483399593904f;     // sqrt(2048)
  const float c = -9.210340371976184f / 2048.f;  // -ln(10000)/H
  for (int h = threadIdx.x; h < 2048; h += 256) {
    int i = h >> 1;
    float dv = expf((float)(2 * i) * c);
    float ang = (float)b * dv;
    float pe = (h & 1) ? cosf(ang) : sinf(ang);
    float val = emb[(size_t)tok * 2048 + h] * sqrtH + pe;
    x[(size_t)row * 2048 + h] = val;
    xbf[(size_t)row * 2048 + h] = f2bf(val);
  }
}

// ---------------- bf16 MFMA GEMM: C[M,N] = A_bf16[M,2048] @ B_f32[2048,N] + bias ---------------
// Block: 256 threads (4 waves, 2x2), tile BM x 128, BK=32, double-buffered.
template <int BM>
__global__ __launch_bounds__(256) void gemm_kernel(
    const unsigned short* __restrict__ A, const float* __restrict__ B,
    const float* __restrict__ bias, float* __restrict__ C, const int N) {
  constexpr int K = 2048;
  constexpr int WM = BM / 32;                 // A-frags per wave
  constexpr int AI = BM / 64;                 // uint4 staging loads per thread
  __shared__ __align__(16) unsigned short A_lds[2][BM * 32];
  __shared__ __align__(16) unsigned short B_lds[2][128 * 32];

  const int tid = threadIdx.x;
  const int m0 = blockIdx.x * BM;             // x = M (fastest) -> B-slice reuse is concurrent
  const int n0 = blockIdx.y * 128;
  const int w = tid >> 6, lane = tid & 63;
  const int wm = w >> 1, wn = w & 1;

  // B staging: thread (n_local = tid&127, kq = tid>>7) covers column n_local, k-offset kq*4 in
  // each 8-k chunk. Loads are coalesced dwords (consecutive lanes -> consecutive columns).
  const int n_local = tid & 127;
  const int kq = tid >> 7;                    // 0..1
  const int col = n0 + n_local;
  const bool colok = col < N;
  const int bswz = (n_local >> 1) & 3;

  // A staging: flat = i*256+tid -> row flat>>2, global chunk flat&3 (coalesced uint4).
  // fragment read offsets, constant across K-tiles (chunk = (lane>>4) ^ ((row>>1)&3))
  int aOff[WM], bOff[4];
#pragma unroll
  for (int mi = 0; mi < WM; ++mi) {
    int m = wm * (BM / 2) + mi * 16 + (lane & 15);
    aOff[mi] = m * 32 + ((lane >> 4) ^ ((m >> 1) & 3)) * 8;
  }
#pragma unroll
  for (int ni = 0; ni < 4; ++ni) {
    int n = wn * 64 + ni * 16 + (lane & 15);
    bOff[ni] = n * 32 + ((lane >> 4) ^ ((n >> 1) & 3)) * 8;
  }

  f32x4 acc[WM][4] = {};
  float fB[16];
  uint4 fA[AI];

  auto loadB = [&](int k0) {
#pragma unroll
    for (int g = 0; g < 4; ++g) {
      int kl = (g * 2 + kq) * 4;
#pragma unroll
      for (int i = 0; i < 4; ++i)
        fB[g * 4 + i] = colok ? B[(size_t)(k0 + kl + i) * N + col] : 0.f;
    }
  };
  auto loadA = [&](int k0) {
#pragma unroll
    for (int i = 0; i < AI; ++i) {
      int flat = i * 256 + tid;
      int row = flat >> 2, cg = flat & 3;
      fA[i] = *(const uint4*)(A + (size_t)(m0 + row) * K + k0 + cg * 8);
    }
  };
  auto writeB = [&](int bf) {
#pragma unroll
    for (int g = 0; g < 4; ++g) {
      int kl = (g * 2 + kq) * 4;
      unsigned int lo = (unsigned int)f2bf(fB[g * 4 + 0]) | ((unsigned int)f2bf(fB[g * 4 + 1]) << 16);
      unsigned int hi = (unsigned int)f2bf(fB[g * 4 + 2]) | ((unsigned int)f2bf(fB[g * 4 + 3]) << 16);
      int chunk = (kl >> 3) ^ bswz;
      *(uint2*)&B_lds[bf][n_local * 32 + chunk * 8 + (kl & 7)] = make_uint2(lo, hi);
    }
  };
  auto writeA = [&](int bf) {
#pragma unroll
    for (int i = 0; i < AI; ++i) {
      int flat = i * 256 + tid;
      int row = flat >> 2, cg = flat & 3;
      *(uint4*)&A_lds[bf][row * 32 + (cg ^ ((row >> 1) & 3)) * 8] = fA[i];
    }
  };
  auto compute = [&](int bf) {
    bf16x8 af[WM], bfr[4];
#pragma unroll
    for (int mi = 0; mi < WM; ++mi) af[mi] = *(const bf16x8*)&A_lds[bf][aOff[mi]];
#pragma unroll
    for (int ni = 0; ni < 4; ++ni) bfr[ni] = *(const bf16x8*)&B_lds[bf][bOff[ni]];
#pragma unroll
    for (int mi = 0; mi < WM; ++mi)
#pragma unroll
      for (int ni = 0; ni < 4; ++ni)
        acc[mi][ni] = __builtin_amdgcn_mfma_f32_16x16x32_bf16(af[mi], bfr[ni], acc[mi][ni], 0, 0, 0);
  };

  // prologue: stage tile 0
  loadB(0); loadA(0);
  writeB(0); writeA(0);
  __syncthreads();
  int buf = 0;
  for (int t = 0; t < K / 32 - 1; ++t) {
    loadB((t + 1) * 32);   // issue next-tile global loads (no wait)
    loadA((t + 1) * 32);
    compute(buf);          // MFMA on current tile hides the load latency
    writeB(buf ^ 1);       // waits on loads, cvt, ds_write other buffer
    writeA(buf ^ 1);
    __syncthreads();
    buf ^= 1;
  }
  compute(buf);

  const int r0w = (lane >> 4) * 4;            // C/D: col = lane&15, row = (lane>>4)*4 + reg
  const int lrow = lane & 15;
#pragma unroll
  for (int mi = 0; mi < WM; ++mi)
#pragma unroll
    for (int ni = 0; ni < 4; ++ni) {
      int ccol = n0 + wn * 64 + ni * 16 + lrow;
      if (ccol < N) {
        float bv = bias[ccol];
#pragma unroll
        for (int r = 0; r < 4; ++r) {
          int crow = m0 + wm * (BM / 2) + mi * 16 + r0w + r;
          C[(size_t)crow * N + ccol] = acc[mi][ni][r] + bv;
        }
      }
    }
}

// ---------------- fused attention: scores -> softmax -> exp -> renorm(+eps) -> a2*sigmoid(a2) -> @V
__global__ __launch_bounds__(256) void attn_kernel(
    const float* __restrict__ q, const float* __restrict__ k,
    const float* __restrict__ v, unsigned short* __restrict__ o) {
  __shared__ __align__(16) float K_lds[512 * 32];   // 64KB
  const int tid = threadIdx.x;
  const int blk = blockIdx.x;                 // 0..255
  const int bh = blk >> 1, chunk = blk & 1;
  const int b = bh >> 6, h = bh & 63;
  const size_t headoff = (size_t)b * 512 * 2048 + (size_t)h * 32;

  const float* kb = k + headoff;
#pragma unroll
  for (int i = 0; i < 16; ++i) {
    int flat = i * 256 + tid;                 // float4 id (4096 total)
    int j = flat >> 3, d4 = flat & 7;
    *(float4*)&K_lds[j * 32 + d4 * 4] = *(const float4*)(kb + (size_t)j * 2048 + d4 * 4);
  }
  __syncthreads();

  const int row = chunk * 256 + tid;          // s in [0,512)
  const float* qr = q + headoff + (size_t)row * 2048;
  float4 Q[8];
#pragma unroll
  for (int d = 0; d < 8; ++d) Q[d] = *(const float4*)(qr + d * 4);

  const float scale = 0.17677669529663689f;   // 1/sqrt(32)
  auto dot = [&](int j) -> float {
    const float4* kr = (const float4*)&K_lds[j * 32];
    float p0 = 0.f, p1 = 0.f, p2 = 0.f, p3 = 0.f;
#pragma unroll
    for (int d = 0; d < 8; ++d) {
      float4 kk = kr[d];
      p0 = fmaf(Q[d].x, kk.x, p0);
      p1 = fmaf(Q[d].y, kk.y, p1);
      p2 = fmaf(Q[d].z, kk.z, p2);
      p3 = fmaf(Q[d].w, kk.w, p3);
    }
    return ((p0 + p1) + (p2 + p3)) * scale;
  };

  // pass 1: online max + softmax denominator
  float m = -1e30f, denom = 0.f;
  for (int j = 0; j < 512; ++j) {
    float s = dot(j);
    float nm = fmaxf(m, s);
    denom = denom * __expf(m - nm) + __expf(s - nm);
    m = nm;
  }
  const float invd = 1.f / denom;

  // pass 2: sum of exp(softmax)
  float sum_e = 0.f;
  for (int j = 0; j < 512; ++j) {
    float a = __expf(dot(j) - m) * invd;
    sum_e += __expf(a);
  }
  const float inv_se = 1.f / (sum_e + 1e-6f);

  // pass 3: cw = a2*sigmoid(a2), accumulate cw @ V
  float4 accv[8];
#pragma unroll
  for (int d = 0; d < 8; ++d) accv[d] = make_float4(0.f, 0.f, 0.f, 0.f);
  const float* vb = v + headoff;
  for (int j = 0; j < 512; ++j) {
    float a = __expf(dot(j) - m) * invd;
    float e = __expf(a);
    float a2 = e * inv_se;
    float cw = a2 / (1.f + __expf(-a2));
    const float4* vr = (const float4*)(vb + (size_t)j * 2048);
#pragma unroll
    for (int d = 0; d < 8; ++d) {
      float4 vv = vr[d];
      accv[d].x = fmaf(cw, vv.x, accv[d].x);
      accv[d].y = fmaf(cw, vv.y, accv[d].y);
      accv[d].z = fmaf(cw, vv.z, accv[d].z);
      accv[d].w = fmaf(cw, vv.w, accv[d].w);
    }
  }
  unsigned short* orow = o + headoff + (size_t)row * 2048;
#pragma unroll
  for (int d = 0; d < 8; ++d) {
    orow[d * 4 + 0] = f2bf(accv[d].x);
    orow[d * 4 + 1] = f2bf(accv[d].y);
    orow[d * 4 + 2] = f2bf(accv[d].z);
    orow[d * 4 + 3] = f2bf(accv[d].w);
  }
}

// ---------------- residual + sr_norm with quake fast_inv_sqrt (bit-faithful) -------------------
__global__ __launch_bounds__(256) void norm_kernel(
    const float* __restrict__ o, const float* __restrict__ xin,
    const float* __restrict__ w, const float* __restrict__ bb,
    float* __restrict__ xout, unsigned short* __restrict__ xbf) {
  __shared__ float red[4];
  const int row = blockIdx.x, tid = threadIdx.x;
  const float* op = o + (size_t)row * 2048;
  const float* xp = xin + (size_t)row * 2048;
  float4 hv[2];
#pragma unroll
  for (int i = 0; i < 2; ++i) {
    float4 a = *(const float4*)(op + tid * 4 + i * 1024);
    float4 c = *(const float4*)(xp + tid * 4 + i * 1024);
    hv[i] = make_float4(a.x + c.x, a.y + c.y, a.z + c.z, a.w + c.w);
  }
  float s = 0.f;
#pragma unroll
  for (int i = 0; i < 2; ++i) s += hv[i].x + hv[i].y + hv[i].z + hv[i].w;
  for (int off = 32; off; off >>= 1) s += __shfl_down(s, off);
  if ((tid & 63) == 0) red[tid >> 6] = s;
  __syncthreads();
  const float mean = (red[0] + red[1] + red[2] + red[3]) * (1.f / 2048.f);
  __syncthreads();

  float vs = 0.f;
#pragma unroll
  for (int i = 0; i < 2; ++i) {
    float dx = hv[i].x - mean, dy = hv[i].y - mean, dz = hv[i].z - mean, dw = hv[i].w - mean;
    vs += dx * dx + dy * dy + dz * dz + dw * dw;
  }
  for (int off = 32; off; off >>= 1) vs += __shfl_down(vs, off);
  if ((tid & 63) == 0) red[tid >> 6] = vs;
  __syncthreads();
  const float var = (red[0] + red[1] + red[2] + red[3]) * (1.f / 2048.f);

  // quake fast inverse sqrt, exactly as reference
  const float xv = var + 1e-5f;
  int ii = __float_as_int(xv);
  ii = 1597463007 - (ii >> 1);
  float y = __int_as_float(ii);
  y = y * (1.5f - 0.5f * xv * y * y);

#pragma unroll
  for (int i = 0; i < 2; ++i) {
    int c0 = tid * 4 + i * 1024;
    float4 wv = *(const float4*)(w + c0);
    float4 bv = *(const float4*)(bb + c0);
    float r0 = wv.x * ((hv[i].x - mean) * y) + bv.x;
    float r1 = wv.y * ((hv[i].y - mean) * y) + bv.y;
    float r2 = wv.z * ((hv[i].z - mean) * y) + bv.z;
    float r3 = wv.w * ((hv[i].w - mean) * y) + bv.w;
    *(float4*)(xout + (size_t)row * 2048 + c0) = make_float4(r0, r1, r2, r3);
    unsigned short* xb = xbf + (size_t)row * 2048 + c0;
    xb[0] = f2bf(r0); xb[1] = f2bf(r1); xb[2] = f2bf(r2); xb[3] = f2bf(r3);
  }
}

// ---------------- launch -----------------------------------------------------------------------
extern "C" void kernel_launch(void* const* d_in, const int* in_sizes, int n_in,
                              void* d_out, int out_size, void* d_ws, size_t ws_size,
                              hipStream_t stream) {
  const int*   src  = (const int*)d_in[0];
  const float* emb  = (const float*)d_in[1];
  const float* Wq   = (const float*)d_in[2];
  const float* bq   = (const float*)d_in[3];
  const float* Wk   = (const float*)d_in[4];
  const float* bk   = (const float*)d_in[5];
  const float* Wv   = (const float*)d_in[6];
  const float* bv   = (const float*)d_in[7];
  const float* Wo   = (const float*)d_in[8];
  const float* bo   = (const float*)d_in[9];
  const float* nw   = (const float*)d_in[10];
  const float* nb   = (const float*)d_in[11];
  const float* Wout = (const float*)d_in[12];
  const float* bout = (const float*)d_in[13];
  float* out = (float*)d_out;

  char* ws = (char*)d_ws;
  float* x  = (float*)(ws);
  float* qb = (float*)(ws + (8ll << 20));
  float* kb = (float*)(ws + (16ll << 20));
  float* vb = (float*)(ws + (24ll << 20));
  float* ob = (float*)(ws + (32ll << 20));
  unsigned short* xbf = (unsigned short*)(ws + (40ll << 20));
  unsigned short* abf = (unsigned short*)(ws + (44ll << 20));

  embed_kernel<<<1024, 256, 0, stream>>>(src, emb, x, xbf);

  const dim3 gproj(16, 16);   // x = M-blocks (16x64), y = N-blocks (16x128)
  for (int l = 0; l < 2; ++l) {
    const size_t wo_ = (size_t)l * 2048 * 2048;
    const size_t bo_ = (size_t)l * 2048;
    gemm_kernel<64><<<gproj, 256, 0, stream>>>(xbf, Wq + wo_, bq + bo_, qb, 2048);
    gemm_kernel<64><<<gproj, 256, 0, stream>>>(xbf, Wk + wo_, bk + bo_, kb, 2048);
    gemm_kernel<64><<<gproj, 256, 0, stream>>>(xbf, Wv + wo_, bv + bo_, vb, 2048);
    attn_kernel<<<256, 256, 0, stream>>>(qb, kb, vb, abf);
    gemm_kernel<64><<<gproj, 256, 0, stream>>>(abf, Wo + wo_, bo + bo_, ob, 2048);
    norm_kernel<<<1024, 256, 0, stream>>>(ob, x, nw + bo_, nb + bo_, x, xbf);
  }

  // final: M=1024 (8 blocks, fastest) x N=100000 (782 blocks)
  const dim3 gfin(8, (100000 + 127) / 128);
  gemm_kernel<128><<<gfin, 256, 0, stream>>>(xbf, Wout, bout, out, 100000);
}

// Round 4
// 2094.640 us; speedup vs baseline: 2.2508x; 1.3622x over previous
//
#include <hip/hip_runtime.h>

// QuantumMicroTransformer forward, MI355X (gfx950).
// GEMMs: bf16 MFMA 16x16x32, double-buffered (1 barrier/K-tile):
//   A (bf16): global_load_lds dwordx4, chunk-XOR swizzle folded into the per-lane GLOBAL address
//             (LDS dest linear per m173/rule-21), conflict-free ds_read_b128.
//   B (fp32): coalesced dword loads -> regs -> cvt bf16 -> swizzled ds_write (as Round 3, proven).
// Final GEMM: 1-D grid with bijective XCD-chunked swizzle (6256 % 8 == 0) so the 8 M-blocks
//   sharing a B-window are consecutive on ONE XCD -> B reuse hits that XCD's L2.
// QKV projections fused into one dispatch via blockIdx.z.

#define DEVINL __device__ __forceinline__

typedef float f32x4 __attribute__((ext_vector_type(4)));
typedef __bf16 bf16x8 __attribute__((ext_vector_type(8)));

DEVINL unsigned short f2bf(float f) {
  unsigned int u = __float_as_uint(f);
  u += 0x7fffu + ((u >> 16) & 1u);   // round-to-nearest-even
  return (unsigned short)(u >> 16);
}

DEVINL void gload_lds16(const void* g, void* l) {
  __builtin_amdgcn_global_load_lds(
      (const __attribute__((address_space(1))) unsigned int*)g,
      (__attribute__((address_space(3))) unsigned int*)l, 16, 0, 0);
}

// ---------------- embed + positional encoding (pe indexed by BATCH, per reference) -------------
__global__ __launch_bounds__(256) void embed_kernel(
    const int* __restrict__ src, const float* __restrict__ emb,
    float* __restrict__ x, unsigned short* __restrict__ xbf) {
  const int row = blockIdx.x;                 // b*512 + s
  const int b = row >> 9;
  const int tok = src[row];
  const float sqrtH = 45.25483399593904f;     // sqrt(2048)
  const float c = -9.210340371976184f / 2048.f;  // -ln(10000)/H
  for (int h = threadIdx.x; h < 2048; h += 256) {
    int i = h >> 1;
    float dv = expf((float)(2 * i) * c);
    float ang = (float)b * dv;
    float pe = (h & 1) ? cosf(ang) : sinf(ang);
    float val = emb[(size_t)tok * 2048 + h] * sqrtH + pe;
    x[(size_t)row * 2048 + h] = val;
    xbf[(size_t)row * 2048 + h] = f2bf(val);
  }
}

// ---------------- bf16 MFMA GEMM body: C[M,N] = A_bf16[M,2048] @ B_f32[2048,N] + bias ----------
// 256 threads (4 waves, 2x2), tile BM x 128, BK=32, double-buffered, 1 barrier/K-tile.
template <int BM>
DEVINL void gemm_body(const unsigned short* __restrict__ A, const float* __restrict__ B,
                      const float* __restrict__ bias, float* __restrict__ C,
                      const int N, const int m0, const int n0) {
  constexpr int K = 2048;
  constexpr int WM = BM / 32;                 // A-frags per wave
  constexpr int AI = BM / 64;                 // global_load_lds instrs per wave
  __shared__ __align__(16) unsigned short A_lds[2][BM * 32];
  __shared__ __align__(16) unsigned short B_lds[2][128 * 32];

  const int tid = threadIdx.x;
  const int w = tid >> 6, lane = tid & 63;
  const int wm = w >> 1, wn = w & 1;

  // B staging: thread (n_local = tid&127, kq = tid>>7) covers column n_local, k-offset kq*4 in
  // each 8-k chunk. Loads are coalesced dwords (consecutive lanes -> consecutive columns).
  const int n_local = tid & 127;
  const int kq = tid >> 7;                    // 0..1
  const int col = n0 + n_local;
  const bool colok = col < N;
  const int bswz = (n_local >> 1) & 3;

  // A staging via global_load_lds: instr covers 16 rows; lane l -> row r0+(l>>2), LDS chunk l&3.
  // Source chunk pre-swizzled: (l&3) ^ ((row>>1)&3) == (l&3) ^ ((l>>3)&3) since r0 % 16 == 0.
  const int aRow = lane >> 2;
  const int aChunk = (lane & 3) ^ ((lane >> 3) & 3);

  // fragment read offsets, constant across K-tiles (chunk = (lane>>4) ^ ((row>>1)&3))
  int aOff[WM], bOff[4];
#pragma unroll
  for (int mi = 0; mi < WM; ++mi) {
    int m = wm * (BM / 2) + mi * 16 + (lane & 15);
    aOff[mi] = m * 32 + ((lane >> 4) ^ ((m >> 1) & 3)) * 8;
  }
#pragma unroll
  for (int ni = 0; ni < 4; ++ni) {
    int n = wn * 64 + ni * 16 + (lane & 15);
    bOff[ni] = n * 32 + ((lane >> 4) ^ ((n >> 1) & 3)) * 8;
  }

  f32x4 acc[WM][4] = {};
  float fB[16];

  auto stageA = [&](int k0, int bf) {
#pragma unroll
    for (int i = 0; i < AI; ++i) {
      int r0 = (w * AI + i) * 16;
      gload_lds16(A + (size_t)(m0 + r0 + aRow) * K + k0 + aChunk * 8,
                  &A_lds[bf][r0 * 32]);
    }
  };
  auto loadB = [&](int k0) {
#pragma unroll
    for (int g = 0; g < 4; ++g) {
      int kl = (g * 2 + kq) * 4;
#pragma unroll
      for (int i = 0; i < 4; ++i)
        fB[g * 4 + i] = colok ? B[(size_t)(k0 + kl + i) * N + col] : 0.f;
    }
  };
  auto writeB = [&](int bf) {
#pragma unroll
    for (int g = 0; g < 4; ++g) {
      int kl = (g * 2 + kq) * 4;
      unsigned int lo = (unsigned int)f2bf(fB[g * 4 + 0]) | ((unsigned int)f2bf(fB[g * 4 + 1]) << 16);
      unsigned int hi = (unsigned int)f2bf(fB[g * 4 + 2]) | ((unsigned int)f2bf(fB[g * 4 + 3]) << 16);
      int chunk = (kl >> 3) ^ bswz;
      *(uint2*)&B_lds[bf][n_local * 32 + chunk * 8 + (kl & 7)] = make_uint2(lo, hi);
    }
  };
  auto compute = [&](int bf) {
    bf16x8 af[WM], bfr[4];
#pragma unroll
    for (int mi = 0; mi < WM; ++mi) af[mi] = *(const bf16x8*)&A_lds[bf][aOff[mi]];
#pragma unroll
    for (int ni = 0; ni < 4; ++ni) bfr[ni] = *(const bf16x8*)&B_lds[bf][bOff[ni]];
#pragma unroll
    for (int mi = 0; mi < WM; ++mi)
#pragma unroll
      for (int ni = 0; ni < 4; ++ni)
        acc[mi][ni] = __builtin_amdgcn_mfma_f32_16x16x32_bf16(af[mi], bfr[ni], acc[mi][ni], 0, 0, 0);
  };

  // prologue: stage tile 0
  stageA(0, 0);
  loadB(0);
  writeB(0);
  __syncthreads();
  int buf = 0;
  for (int t = 0; t < K / 32 - 1; ++t) {
    stageA((t + 1) * 32, buf ^ 1);  // async A -> other LDS buffer
    loadB((t + 1) * 32);            // issue B global loads (no wait)
    compute(buf);                   // MFMA on current tile hides the load latency
    writeB(buf ^ 1);                // waits on B loads, cvt, ds_write other buffer
    __syncthreads();                // drains gload_lds (vmcnt) + ds_writes
    buf ^= 1;
  }
  compute(buf);

  const int r0w = (lane >> 4) * 4;            // C/D: col = lane&15, row = (lane>>4)*4 + reg
  const int lrow = lane & 15;
#pragma unroll
  for (int mi = 0; mi < WM; ++mi)
#pragma unroll
    for (int ni = 0; ni < 4; ++ni) {
      int ccol = n0 + wn * 64 + ni * 16 + lrow;
      if (ccol < N) {
        float bv = bias[ccol];
#pragma unroll
        for (int r = 0; r < 4; ++r) {
          int crow = m0 + wm * (BM / 2) + mi * 16 + r0w + r;
          C[(size_t)crow * N + ccol] = acc[mi][ni][r] + bv;
        }
      }
    }
}

// generic 2-D grid version (O-proj)
template <int BM>
__global__ __launch_bounds__(256) void gemm_kernel(
    const unsigned short* __restrict__ A, const float* __restrict__ B,
    const float* __restrict__ bias, float* __restrict__ C, const int N) {
  gemm_body<BM>(A, B, bias, C, N, blockIdx.x * BM, blockIdx.y * 128);
}

// fused QKV: blockIdx.z selects weight/bias/output
__global__ __launch_bounds__(256) void gemm_qkv_kernel(
    const unsigned short* __restrict__ A,
    const float* __restrict__ Wq, const float* __restrict__ Wk, const float* __restrict__ Wv,
    const float* __restrict__ bq, const float* __restrict__ bk, const float* __restrict__ bv,
    float* __restrict__ q, float* __restrict__ k, float* __restrict__ v) {
  const int z = blockIdx.z;
  const float* B = (z == 0) ? Wq : (z == 1) ? Wk : Wv;
  const float* bias = (z == 0) ? bq : (z == 1) ? bk : bv;
  float* C = (z == 0) ? q : (z == 1) ? k : v;
  gemm_body<64>(A, B, bias, C, 2048, blockIdx.x * 64, blockIdx.y * 128);
}

// final GEMM: 1-D grid, bijective XCD-chunked swizzle (gridDim.x % 8 == 0).
// f = (bid%8)*chunk + bid/8 ; m-block = f%8 (8 M-blocks of 128), n-block = f/8.
__global__ __launch_bounds__(256) void gemm_final_kernel(
    const unsigned short* __restrict__ A, const float* __restrict__ B,
    const float* __restrict__ bias, float* __restrict__ C, const int N) {
  const int bid = blockIdx.x;
  const int f = (bid & 7) * (gridDim.x >> 3) + (bid >> 3);
  gemm_body<128>(A, B, bias, C, N, (f & 7) * 128, (f >> 3) * 128);
}

// ---------------- fused attention: scores -> softmax -> exp -> renorm(+eps) -> a2*sigmoid(a2) -> @V
__global__ __launch_bounds__(256) void attn_kernel(
    const float* __restrict__ q, const float* __restrict__ k,
    const float* __restrict__ v, unsigned short* __restrict__ o) {
  __shared__ __align__(16) float K_lds[512 * 32];   // 64KB
  const int tid = threadIdx.x;
  const int blk = blockIdx.x;                 // 0..255
  const int bh = blk >> 1, chunk = blk & 1;
  const int b = bh >> 6, h = bh & 63;
  const size_t headoff = (size_t)b * 512 * 2048 + (size_t)h * 32;

  const float* kb = k + headoff;
#pragma unroll
  for (int i = 0; i < 16; ++i) {
    int flat = i * 256 + tid;                 // float4 id (4096 total)
    int j = flat >> 3, d4 = flat & 7;
    *(float4*)&K_lds[j * 32 + d4 * 4] = *(const float4*)(kb + (size_t)j * 2048 + d4 * 4);
  }
  __syncthreads();

  const int row = chunk * 256 + tid;          // s in [0,512)
  const float* qr = q + headoff + (size_t)row * 2048;
  float4 Q[8];
#pragma unroll
  for (int d = 0; d < 8; ++d) Q[d] = *(const float4*)(qr + d * 4);

  const float scale = 0.17677669529663689f;   // 1/sqrt(32)
  auto dot = [&](int j) -> float {
    const float4* kr = (const float4*)&K_lds[j * 32];
    float p0 = 0.f, p1 = 0.f, p2 = 0.f, p3 = 0.f;
#pragma unroll
    for (int d = 0; d < 8; ++d) {
      float4 kk = kr[d];
      p0 = fmaf(Q[d].x, kk.x, p0);
      p1 = fmaf(Q[d].y, kk.y, p1);
      p2 = fmaf(Q[d].z, kk.z, p2);
      p3 = fmaf(Q[d].w, kk.w, p3);
    }
    return ((p0 + p1) + (p2 + p3)) * scale;
  };

  // pass 1: online max + softmax denominator
  float m = -1e30f, denom = 0.f;
  for (int j = 0; j < 512; ++j) {
    float s = dot(j);
    float nm = fmaxf(m, s);
    denom = denom * __expf(m - nm) + __expf(s - nm);
    m = nm;
  }
  const float invd = 1.f / denom;

  // pass 2: sum of exp(softmax)
  float sum_e = 0.f;
  for (int j = 0; j < 512; ++j) {
    float a = __expf(dot(j) - m) * invd;
    sum_e += __expf(a);
  }
  const float inv_se = 1.f / (sum_e + 1e-6f);

  // pass 3: cw = a2*sigmoid(a2), accumulate cw @ V (V row software-prefetched)
  float4 accv[8];
#pragma unroll
  for (int d = 0; d < 8; ++d) accv[d] = make_float4(0.f, 0.f, 0.f, 0.f);
  const float* vb = v + headoff;
  float4 vcur[8];
#pragma unroll
  for (int d = 0; d < 8; ++d) vcur[d] = ((const float4*)vb)[d];
  for (int j = 0; j < 512; ++j) {
    float4 vnxt[8];
    if (j < 511) {
      const float4* vr = (const float4*)(vb + (size_t)(j + 1) * 2048);
#pragma unroll
      for (int d = 0; d < 8; ++d) vnxt[d] = vr[d];
    } else {
#pragma unroll
      for (int d = 0; d < 8; ++d) vnxt[d] = vcur[d];
    }
    float a = __expf(dot(j) - m) * invd;
    float e = __expf(a);
    float a2 = e * inv_se;
    float cw = a2 / (1.f + __expf(-a2));
#pragma unroll
    for (int d = 0; d < 8; ++d) {
      accv[d].x = fmaf(cw, vcur[d].x, accv[d].x);
      accv[d].y = fmaf(cw, vcur[d].y, accv[d].y);
      accv[d].z = fmaf(cw, vcur[d].z, accv[d].z);
      accv[d].w = fmaf(cw, vcur[d].w, accv[d].w);
    }
#pragma unroll
    for (int d = 0; d < 8; ++d) vcur[d] = vnxt[d];
  }
  unsigned short* orow = o + headoff + (size_t)row * 2048;
#pragma unroll
  for (int d = 0; d < 8; ++d) {
    orow[d * 4 + 0] = f2bf(accv[d].x);
    orow[d * 4 + 1] = f2bf(accv[d].y);
    orow[d * 4 + 2] = f2bf(accv[d].z);
    orow[d * 4 + 3] = f2bf(accv[d].w);
  }
}

// ---------------- residual + sr_norm with quake fast_inv_sqrt (bit-faithful) -------------------
__global__ __launch_bounds__(256) void norm_kernel(
    const float* __restrict__ o, const float* __restrict__ xin,
    const float* __restrict__ w, const float* __restrict__ bb,
    float* __restrict__ xout, unsigned short* __restrict__ xbf) {
  __shared__ float red[4];
  const int row = blockIdx.x, tid = threadIdx.x;
  const float* op = o + (size_t)row * 2048;
  const float* xp = xin + (size_t)row * 2048;
  float4 hv[2];
#pragma unroll
  for (int i = 0; i < 2; ++i) {
    float4 a = *(const float4*)(op + tid * 4 + i * 1024);
    float4 c = *(const float4*)(xp + tid * 4 + i * 1024);
    hv[i] = make_float4(a.x + c.x, a.y + c.y, a.z + c.z, a.w + c.w);
  }
  float s = 0.f;
#pragma unroll
  for (int i = 0; i < 2; ++i) s += hv[i].x + hv[i].y + hv[i].z + hv[i].w;
  for (int off = 32; off; off >>= 1) s += __shfl_down(s, off);
  if ((tid & 63) == 0) red[tid >> 6] = s;
  __syncthreads();
  const float mean = (red[0] + red[1] + red[2] + red[3]) * (1.f / 2048.f);
  __syncthreads();

  float vs = 0.f;
#pragma unroll
  for (int i = 0; i < 2; ++i) {
    float dx = hv[i].x - mean, dy = hv[i].y - mean, dz = hv[i].z - mean, dw = hv[i].w - mean;
    vs += dx * dx + dy * dy + dz * dz + dw * dw;
  }
  for (int off = 32; off; off >>= 1) vs += __shfl_down(vs, off);
  if ((tid & 63) == 0) red[tid >> 6] = vs;
  __syncthreads();
  const float var = (red[0] + red[1] + red[2] + red[3]) * (1.f / 2048.f);

  // quake fast inverse sqrt, exactly as reference
  const float xv = var + 1e-5f;
  int ii = __float_as_int(xv);
  ii = 1597463007 - (ii >> 1);
  float y = __int_as_float(ii);
  y = y * (1.5f - 0.5f * xv * y * y);

#pragma unroll
  for (int i = 0; i < 2; ++i) {
    int c0 = tid * 4 + i * 1024;
    float4 wv = *(const float4*)(w + c0);
    float4 bv = *(const float4*)(bb + c0);
    float r0 = wv.x * ((hv[i].x - mean) * y) + bv.x;
    float r1 = wv.y * ((hv[i].y - mean) * y) + bv.y;
    float r2 = wv.z * ((hv[i].z - mean) * y) + bv.z;
    float r3 = wv.w * ((hv[i].w - mean) * y) + bv.w;
    *(float4*)(xout + (size_t)row * 2048 + c0) = make_float4(r0, r1, r2, r3);
    unsigned short* xb = xbf + (size_t)row * 2048 + c0;
    xb[0] = f2bf(r0); xb[1] = f2bf(r1); xb[2] = f2bf(r2); xb[3] = f2bf(r3);
  }
}

// ---------------- launch -----------------------------------------------------------------------
extern "C" void kernel_launch(void* const* d_in, const int* in_sizes, int n_in,
                              void* d_out, int out_size, void* d_ws, size_t ws_size,
                              hipStream_t stream) {
  const int*   src  = (const int*)d_in[0];
  const float* emb  = (const float*)d_in[1];
  const float* Wq   = (const float*)d_in[2];
  const float* bq   = (const float*)d_in[3];
  const float* Wk   = (const float*)d_in[4];
  const float* bk   = (const float*)d_in[5];
  const float* Wv   = (const float*)d_in[6];
  const float* bv   = (const float*)d_in[7];
  const float* Wo   = (const float*)d_in[8];
  const float* bo   = (const float*)d_in[9];
  const float* nw   = (const float*)d_in[10];
  const float* nb   = (const float*)d_in[11];
  const float* Wout = (const float*)d_in[12];
  const float* bout = (const float*)d_in[13];
  float* out = (float*)d_out;

  char* ws = (char*)d_ws;
  float* x  = (float*)(ws);
  float* qb = (float*)(ws + (8ll << 20));
  float* kb = (float*)(ws + (16ll << 20));
  float* vb = (float*)(ws + (24ll << 20));
  float* ob = (float*)(ws + (32ll << 20));
  unsigned short* xbf = (unsigned short*)(ws + (40ll << 20));
  unsigned short* abf = (unsigned short*)(ws + (44ll << 20));

  embed_kernel<<<1024, 256, 0, stream>>>(src, emb, x, xbf);

  for (int l = 0; l < 2; ++l) {
    const size_t wo_ = (size_t)l * 2048 * 2048;
    const size_t bo_ = (size_t)l * 2048;
    gemm_qkv_kernel<<<dim3(16, 16, 3), 256, 0, stream>>>(
        xbf, Wq + wo_, Wk + wo_, Wv + wo_, bq + bo_, bk + bo_, bv + bo_, qb, kb, vb);
    attn_kernel<<<256, 256, 0, stream>>>(qb, kb, vb, abf);
    gemm_kernel<64><<<dim3(16, 16), 256, 0, stream>>>(abf, Wo + wo_, bo + bo_, ob, 2048);
    norm_kernel<<<1024, 256, 0, stream>>>(ob, x, nw + bo_, nb + bo_, x, xbf);
  }

  // final: 8 M-blocks x 782 N-blocks = 6256 (divisible by 8 -> bijective XCD swizzle)
  gemm_final_kernel<<<8 * 782, 256, 0, stream>>>(xbf, Wout, bout, out, 100000);
}